// Round 2
// baseline (168.555 us; speedup 1.0000x reference)
//
#include <hip/hip_runtime.h>
#include <hip/hip_bf16.h>

using floatx4 = __attribute__((ext_vector_type(4))) float;
using int4v   = __attribute__((ext_vector_type(4))) int;
using int8v   = __attribute__((ext_vector_type(8))) int;

#define TEMP_INV 14.285714285714286f  // 1/0.07
#define DD 256   // feature dim; one fp8 row = 256 B
#define BM 128
#define NCT 8    // column tiles per block -> grid 8x64 = 512 = 2 blocks/CU exact
#define SC1 127  // e8m0 exponent 127 -> scale 1.0

typedef const __attribute__((address_space(1))) unsigned int* gptr_t;
typedef __attribute__((address_space(3))) unsigned int* lptr_t;

__device__ __forceinline__ void async_cp16(const void* g, void* l) {
  __builtin_amdgcn_global_load_lds((gptr_t)g, (lptr_t)l, 16, 0, 0);
}

// ---- kernel 1: L2 normalize rows -> fp8 e4m3, exact fp8 diag dot, and ----
// ---- zero the output scalar (replaces a hipMemsetAsync dispatch).      ----
__global__ __launch_bounds__(256) void nrm_kernel(
    const float* __restrict__ anchor, const float* __restrict__ positive,
    unsigned char* __restrict__ a8, unsigned char* __restrict__ p8,
    float* __restrict__ diag, float* __restrict__ out) {
  if (blockIdx.x == 0 && threadIdx.x == 0) out[0] = 0.f;  // stream-order visible
  const int wave = threadIdx.x >> 6;
  const int lane = threadIdx.x & 63;
  const int row  = blockIdx.x * 4 + wave;
  const float4 va = ((const float4*)(anchor   + (size_t)row * DD))[lane];
  const float4 vp = ((const float4*)(positive + (size_t)row * DD))[lane];
  float sa = va.x * va.x + va.y * va.y + va.z * va.z + va.w * va.w;
  float sp = vp.x * vp.x + vp.y * vp.y + vp.z * vp.z + vp.w * vp.w;
#pragma unroll
  for (int m = 32; m >= 1; m >>= 1) {
    sa += __shfl_xor(sa, m, 64);
    sp += __shfl_xor(sp, m, 64);
  }
  const float ka = 1.0f / fmaxf(sqrtf(sa), 1e-12f);
  const float kp = 1.0f / fmaxf(sqrtf(sp), 1e-12f);
  int pa = __builtin_amdgcn_cvt_pk_fp8_f32(va.x * ka, va.y * ka, 0, false);
  pa     = __builtin_amdgcn_cvt_pk_fp8_f32(va.z * ka, va.w * ka, pa, true);
  int pp = __builtin_amdgcn_cvt_pk_fp8_f32(vp.x * kp, vp.y * kp, 0, false);
  pp     = __builtin_amdgcn_cvt_pk_fp8_f32(vp.z * kp, vp.w * kp, pp, true);
  ((int*)(a8 + (size_t)row * DD))[lane] = pa;
  ((int*)(p8 + (size_t)row * DD))[lane] = pp;
  // exact quantized dot for the diagonal (byte selector must be literal)
  float d = __builtin_amdgcn_cvt_f32_fp8(pa, 0) * __builtin_amdgcn_cvt_f32_fp8(pp, 0)
          + __builtin_amdgcn_cvt_f32_fp8(pa, 1) * __builtin_amdgcn_cvt_f32_fp8(pp, 1)
          + __builtin_amdgcn_cvt_f32_fp8(pa, 2) * __builtin_amdgcn_cvt_f32_fp8(pp, 2)
          + __builtin_amdgcn_cvt_f32_fp8(pa, 3) * __builtin_amdgcn_cvt_f32_fp8(pp, 3);
#pragma unroll
  for (int m = 32; m >= 1; m >>= 1) d += __shfl_xor(d, m, 64);
  if (lane == 0) diag[row] = d;
}

// Fragment read from swizzled LDS tile: slot (row, c) holds global granule
// c ^ (row&15); returns global bytes [ks*128+quad*32 .. +32) of `row`.
__device__ __forceinline__ int8v fragLDS(const unsigned char* S, int row, int ks,
                                         int quad, int l16) {
  const int c0 = ks * 8 + quad * 2;
  const int4v lo = *(const int4v*)(S + row * DD + (((c0 + 0) ^ l16) << 4));
  const int4v hi = *(const int4v*)(S + row * DD + (((c0 + 1) ^ l16) << 4));
  return __builtin_shufflevector(lo, hi, 0, 1, 2, 3, 4, 5, 6, 7);
}

// A fragment straight from global (linear layout, no swizzle): 32 B at g.
__device__ __forceinline__ int8v fragG(const unsigned char* g) {
  const int4v lo = *(const int4v*)(g);
  const int4v hi = *(const int4v*)(g + 16);
  return __builtin_shufflevector(lo, hi, 0, 1, 2, 3, 4, 5, 6, 7);
}

__device__ __forceinline__ floatx4 mfma_sc(int8v a, int8v b, floatx4 c) {
  return __builtin_amdgcn_mfma_scale_f32_16x16x128_f8f6f4(a, b, c, 0, 0, 0,
                                                          SC1, 0, SC1);
}

// ------ kernel 2: 512 threads / 8 waves, 32x64 frags per wave ------
// Phase-locked schedule (T3+T5 from the catalog): each ct = 2 sub-phases of
// {4 ds_read_b128x2 + 2 staging issues} -> s_barrier -> lgkmcnt(0) ->
// setprio(1) 8-MFMA cluster setprio(0) -> s_barrier -> exp/max epilogue.
// Rationale: measured 74% of per-ct wall was pipe-idle (m233's 2-phase stall
// anatomy); phase-locking separates the LDS burst from the MFMA burst and the
// VALU epilogue gives the prefetch (full-iteration distance) its coverage.
// A fragments persistent in registers (ct-invariant); Bs double-buffered.
__global__ __launch_bounds__(512, 4) void gemm_stats(
    const unsigned char* __restrict__ a8, const unsigned char* __restrict__ p8,
    float* __restrict__ rsum, float* __restrict__ rmax, int Btot) {
  __shared__ __align__(16) unsigned char Bs[2][BM * DD];  // 2 x 32 KB
  __shared__ float red_sum[2][BM];
  __shared__ float red_max[2][BM];

  const int t = threadIdx.x;
  const int wave = t >> 6, lane = t & 63;
  const int wm = wave & 3, wn = wave >> 2;      // 4 row-groups x 2 col-groups
  const int quad = lane >> 4, l16 = lane & 15;
  const int row0    = blockIdx.y * BM;
  const int colbase = blockIdx.x * (NCT * BM);
  const bool hasdiag = ((int)(blockIdx.y >> 3) == (int)blockIdx.x);

  // staging decomposition: lane = r4*16 + cg
  const int r4 = lane >> 4;
  const int cg = lane & 15;

  // ---- A fragments: 32 VGPRs, ct-invariant ----
  // rows row0 + wm*32 + mi*16 + l16, K bytes [ks*128 + quad*32, +32)
  int8v a_frag[2][2];
  {
    const unsigned char* ab =
        a8 + (size_t)(row0 + wm * 32 + l16) * DD + quad * 32;
#pragma unroll
    for (int mi = 0; mi < 2; ++mi)
#pragma unroll
      for (int ks = 0; ks < 2; ++ks)
        a_frag[mi][ks] = fragG(ab + mi * 16 * DD + ks * 128);
  }

  // ---- stage B tile for ct=0 into buffer 0 ----
#pragma unroll
  for (int q = 0; q < 4; ++q) {
    const int rb = q * 32 + wave * 4;           // wave-uniform base row
    const int r  = rb + r4;
    async_cp16(p8 + (size_t)(colbase + r) * DD + (cg ^ (r & 15)) * 16,
               &Bs[0][rb * DD]);
  }

  float se_run[2][4], mx_run[2][4];
#pragma unroll
  for (int a = 0; a < 2; ++a)
#pragma unroll
    for (int b = 0; b < 4; ++b) { se_run[a][b] = 0.f; mx_run[a][b] = -INFINITY; }

  for (int ct = 0; ct < NCT; ++ct) {
    // Drains vmcnt: stage(ct) landed (issued a full iteration ago = ample
    // coverage) AND all waves finished reading Bs[(ct+1)&1] during ct-1.
    __syncthreads();

    const unsigned char* Bcur = &Bs[ct & 1][0];
    unsigned char* Bnxt = &Bs[(ct + 1) & 1][0];
    const int colb = colbase + (ct + 1) * BM;
    const bool dostage = (ct + 1 < NCT);
    const int col0 = colbase + ct * BM;

#pragma unroll
    for (int p = 0; p < 2; ++p) {
      // ---- phase p: read window (4 B-frags = 8 ds_read_b128) + stage issue --
      const int nA = 2 * p, nB = 2 * p + 1;
      const int8v bfA0 = fragLDS(Bcur, wn * 64 + nA * 16 + l16, 0, quad, l16);
      const int8v bfA1 = fragLDS(Bcur, wn * 64 + nA * 16 + l16, 1, quad, l16);
      const int8v bfB0 = fragLDS(Bcur, wn * 64 + nB * 16 + l16, 0, quad, l16);
      const int8v bfB1 = fragLDS(Bcur, wn * 64 + nB * 16 + l16, 1, quad, l16);
      if (dostage) {
#pragma unroll
        for (int q = 2 * p; q < 2 * p + 2; ++q) {
          const int rb = q * 32 + wave * 4;
          const int r  = rb + r4;
          async_cp16(p8 + (size_t)(colb + r) * DD + (cg ^ (r & 15)) * 16,
                     Bnxt + rb * DD);
        }
      }
      __builtin_amdgcn_sched_barrier(0);
      __builtin_amdgcn_s_barrier();                 // phase-lock: reads issued
      asm volatile("s_waitcnt lgkmcnt(0)" ::: "memory");
      __builtin_amdgcn_sched_barrier(0);            // rule #18: pin MFMA after

      floatx4 acc[2][2];
#pragma unroll
      for (int a = 0; a < 2; ++a)
#pragma unroll
        for (int b = 0; b < 2; ++b) acc[a][b] = (floatx4){0.f, 0.f, 0.f, 0.f};

      __builtin_amdgcn_s_setprio(1);
      acc[0][0] = mfma_sc(a_frag[0][0], bfA0, acc[0][0]);
      acc[0][0] = mfma_sc(a_frag[0][1], bfA1, acc[0][0]);
      acc[1][0] = mfma_sc(a_frag[1][0], bfA0, acc[1][0]);
      acc[1][0] = mfma_sc(a_frag[1][1], bfA1, acc[1][0]);
      acc[0][1] = mfma_sc(a_frag[0][0], bfB0, acc[0][1]);
      acc[0][1] = mfma_sc(a_frag[0][1], bfB1, acc[0][1]);
      acc[1][1] = mfma_sc(a_frag[1][0], bfB0, acc[1][1]);
      acc[1][1] = mfma_sc(a_frag[1][1], bfB1, acc[1][1]);
      __builtin_amdgcn_s_setprio(0);
      __builtin_amdgcn_sched_barrier(0);
      __builtin_amdgcn_s_barrier();                 // MFMA cluster done

      // ---- per-phase stats epilogue (VALU window; covers staging loads) ----
      // C/D: col=lane&15, row=quad*4+reg. se/mx add order == original
      // (per (mi,reg): ni 0,1 in phase0 then 2,3 in phase1) -> bitwise same.
      if (!hasdiag) {
#pragma unroll
        for (int mi = 0; mi < 2; ++mi)
#pragma unroll
          for (int reg = 0; reg < 4; ++reg)
#pragma unroll
            for (int h = 0; h < 2; ++h) {
              const float s = acc[mi][h][reg];
              se_run[mi][reg] += __expf(s * TEMP_INV);
              mx_run[mi][reg] = fmaxf(mx_run[mi][reg], s);
            }
      } else {
#pragma unroll
        for (int mi = 0; mi < 2; ++mi)
#pragma unroll
          for (int reg = 0; reg < 4; ++reg) {
            const int i = row0 + wm * 32 + mi * 16 + quad * 4 + reg;
#pragma unroll
            for (int h = 0; h < 2; ++h) {
              const float s = acc[mi][h][reg];
              const int j = col0 + wn * 64 + (2 * p + h) * 16 + l16;
              se_run[mi][reg] += __expf(s * TEMP_INV);
              mx_run[mi][reg] = fmaxf(mx_run[mi][reg], (i == j) ? -INFINITY : s);
            }
          }
      }
    }
  }

  // once-per-block 16-lane cross reduction
#pragma unroll
  for (int mi = 0; mi < 2; ++mi) {
#pragma unroll
    for (int reg = 0; reg < 4; ++reg) {
      float se = se_run[mi][reg], mx = mx_run[mi][reg];
#pragma unroll
      for (int m = 1; m < 16; m <<= 1) {
        se += __shfl_xor(se, m, 64);
        mx = fmaxf(mx, __shfl_xor(mx, m, 64));
      }
      if (l16 == 0) {
        const int rb = wm * 32 + mi * 16 + quad * 4 + reg;
        red_sum[wn][rb] = se;
        red_max[wn][rb] = mx;
      }
    }
  }
  __syncthreads();
  if (t < BM) {
    rsum[(size_t)blockIdx.x * Btot + row0 + t] = red_sum[0][t] + red_sum[1][t];
    rmax[(size_t)blockIdx.x * Btot + row0 + t] = fmaxf(red_max[0][t], red_max[1][t]);
  }
}

// ---- kernel 3: per-row loss from partials, block-reduce, atomic mean ----
__global__ __launch_bounds__(256) void row_loss_kernel(
    const float* __restrict__ rsum, const float* __restrict__ rmax,
    const float* __restrict__ diag, float* __restrict__ out, int Btot, int NG) {
  const int i = blockIdx.x * 256 + threadIdx.x;
  float s = 0.f, m = -INFINITY;
  for (int c = 0; c < NG; ++c) {
    s += rsum[(size_t)c * Btot + i];
    m = fmaxf(m, rmax[(size_t)c * Btot + i]);
  }
  float rl = __logf(s + __expf(m * TEMP_INV)) - diag[i] * TEMP_INV;
#pragma unroll
  for (int mm = 32; mm >= 1; mm >>= 1) rl += __shfl_xor(rl, mm, 64);
  __shared__ float red[4];
  if ((threadIdx.x & 63) == 0) red[threadIdx.x >> 6] = rl;
  __syncthreads();
  if (threadIdx.x == 0)
    atomicAdd(out, (red[0] + red[1] + red[2] + red[3]) / (float)Btot);
}

extern "C" void kernel_launch(void* const* d_in, const int* in_sizes, int n_in,
                              void* d_out, int out_size, void* d_ws, size_t ws_size,
                              hipStream_t stream) {
  const float* anchor   = (const float*)d_in[0];
  const float* positive = (const float*)d_in[1];
  const int B  = in_sizes[0] / DD;     // 8192
  const int NG = B / (BM * NCT);       // 8 column groups
  const size_t BD = (size_t)B * DD;

  // ws: a8(2MB) | p8(2MB) | rsum(NG*B) | rmax(NG*B) | diag(B)
  unsigned char* a8 = (unsigned char*)d_ws;
  unsigned char* p8 = a8 + BD;
  float* rsum  = (float*)(p8 + BD);
  float* rmax  = rsum + (size_t)NG * B;
  float* diag  = rmax + (size_t)NG * B;

  nrm_kernel<<<B / 4, 256, 0, stream>>>(anchor, positive, a8, p8, diag,
                                        (float*)d_out);
  dim3 g2(NG, B / BM);
  gemm_stats<<<g2, 512, 0, stream>>>(a8, p8, rsum, rmax, B);
  row_loss_kernel<<<B / 256, 256, 0, stream>>>(rsum, rmax, diag, (float*)d_out, B, NG);
}

// Round 3
// 128.747 us; speedup vs baseline: 1.3092x; 1.3092x over previous
//
#include <hip/hip_runtime.h>
#include <hip/hip_bf16.h>

using floatx4 = __attribute__((ext_vector_type(4))) float;
using int4v   = __attribute__((ext_vector_type(4))) int;
using int8v   = __attribute__((ext_vector_type(8))) int;

#define TEMP_INV 14.285714285714286f  // 1/0.07
#define DD 256   // feature dim; one fp8 row = 256 B
#define BMR 128  // rows per block (A panel, held in registers)
#define BNC 128  // cols per B tile (staged in LDS)
#define NCT 4    // tiles per block -> grid 16x64 = 1024 = 4 blocks/CU exact
#define SC1 127  // e8m0 exponent 127 -> scale 1.0

typedef const __attribute__((address_space(1))) unsigned int* gptr_t;
typedef __attribute__((address_space(3))) unsigned int* lptr_t;

__device__ __forceinline__ void async_cp16(const void* g, void* l) {
  __builtin_amdgcn_global_load_lds((gptr_t)g, (lptr_t)l, 16, 0, 0);
}

// ---- kernel 1: L2 normalize rows -> fp8 e4m3, exact fp8 diag dot, and ----
// ---- zero the output scalar (replaces a hipMemsetAsync dispatch).      ----
__global__ __launch_bounds__(256) void nrm_kernel(
    const float* __restrict__ anchor, const float* __restrict__ positive,
    unsigned char* __restrict__ a8, unsigned char* __restrict__ p8,
    float* __restrict__ diag, float* __restrict__ out) {
  if (blockIdx.x == 0 && threadIdx.x == 0) out[0] = 0.f;  // stream-order visible
  const int wave = threadIdx.x >> 6;
  const int lane = threadIdx.x & 63;
  const int row  = blockIdx.x * 4 + wave;
  const float4 va = ((const float4*)(anchor   + (size_t)row * DD))[lane];
  const float4 vp = ((const float4*)(positive + (size_t)row * DD))[lane];
  float sa = va.x * va.x + va.y * va.y + va.z * va.z + va.w * va.w;
  float sp = vp.x * vp.x + vp.y * vp.y + vp.z * vp.z + vp.w * vp.w;
#pragma unroll
  for (int m = 32; m >= 1; m >>= 1) {
    sa += __shfl_xor(sa, m, 64);
    sp += __shfl_xor(sp, m, 64);
  }
  const float ka = 1.0f / fmaxf(sqrtf(sa), 1e-12f);
  const float kp = 1.0f / fmaxf(sqrtf(sp), 1e-12f);
  int pa = __builtin_amdgcn_cvt_pk_fp8_f32(va.x * ka, va.y * ka, 0, false);
  pa     = __builtin_amdgcn_cvt_pk_fp8_f32(va.z * ka, va.w * ka, pa, true);
  int pp = __builtin_amdgcn_cvt_pk_fp8_f32(vp.x * kp, vp.y * kp, 0, false);
  pp     = __builtin_amdgcn_cvt_pk_fp8_f32(vp.z * kp, vp.w * kp, pp, true);
  ((int*)(a8 + (size_t)row * DD))[lane] = pa;
  ((int*)(p8 + (size_t)row * DD))[lane] = pp;
  // exact quantized dot for the diagonal (byte selector must be literal)
  float d = __builtin_amdgcn_cvt_f32_fp8(pa, 0) * __builtin_amdgcn_cvt_f32_fp8(pp, 0)
          + __builtin_amdgcn_cvt_f32_fp8(pa, 1) * __builtin_amdgcn_cvt_f32_fp8(pp, 1)
          + __builtin_amdgcn_cvt_f32_fp8(pa, 2) * __builtin_amdgcn_cvt_f32_fp8(pp, 2)
          + __builtin_amdgcn_cvt_f32_fp8(pa, 3) * __builtin_amdgcn_cvt_f32_fp8(pp, 3);
#pragma unroll
  for (int m = 32; m >= 1; m >>= 1) d += __shfl_xor(d, m, 64);
  if (lane == 0) diag[row] = d;
}

// Fragment read from swizzled LDS tile: slot (row, c) holds global granule
// c ^ (row&15); returns global bytes [ks*128+quad*32 .. +32) of `row`.
__device__ __forceinline__ int8v fragLDS(const unsigned char* S, int row, int ks,
                                         int quad, int l16) {
  const int c0 = ks * 8 + quad * 2;
  const int4v lo = *(const int4v*)(S + row * DD + (((c0 + 0) ^ l16) << 4));
  const int4v hi = *(const int4v*)(S + row * DD + (((c0 + 1) ^ l16) << 4));
  return __builtin_shufflevector(lo, hi, 0, 1, 2, 3, 4, 5, 6, 7);
}

// A fragment straight from global (linear layout, no swizzle): 32 B at g.
__device__ __forceinline__ int8v fragG(const unsigned char* g) {
  const int4v lo = *(const int4v*)(g);
  const int4v hi = *(const int4v*)(g + 16);
  return __builtin_shufflevector(lo, hi, 0, 1, 2, 3, 4, 5, 6, 7);
}

__device__ __forceinline__ floatx4 mfma_sc(int8v a, int8v b, floatx4 c) {
  return __builtin_amdgcn_mfma_scale_f32_16x16x128_f8f6f4(a, b, c, 0, 0, 0,
                                                          SC1, 0, SC1);
}

// ------ kernel 2: 256 threads / 4 waves; wave owns 32 rows x 128 cols ------
// Round-0 skeleton restored (single-buffer B, stage issued after the read
// barrier and covered by the exp epilogue, NO inline asm / sched walls —
// compiler interleaves freely; round-2's imposed phase-lock was -2.2x).
// The freed 32 KB LDS (A panel in registers) buys 4 blocks/CU instead of 2:
// 4 independent barrier domains per CU de-phase naturally, overlapping one
// block's LDS/staging stall with another's MFMA + exp (m114 mechanism).
// Rows complete within one wave -> no cross-wave reduction, one less barrier.
__global__ __launch_bounds__(256, 4) void gemm_stats(
    const unsigned char* __restrict__ a8, const unsigned char* __restrict__ p8,
    float* __restrict__ rsum, float* __restrict__ rmax, int Btot) {
  __shared__ __align__(16) unsigned char Bs[BNC * DD];  // 32 KB, single buffer

  const int t = threadIdx.x;
  const int wave = t >> 6, lane = t & 63;
  const int quad = lane >> 4, l16 = lane & 15;  // also staging r4 / cg
  const int row0    = blockIdx.y * BMR;
  const int colbase = blockIdx.x * (NCT * BNC);

  // ---- A fragments: 32 VGPRs, ct-invariant ----
  // wave owns rows row0 + wave*32 + {mi*16 + l16}; K bytes [ks*128+quad*32,+32)
  int8v a_frag[2][2];
  {
    const unsigned char* ab =
        a8 + (size_t)(row0 + wave * 32 + l16) * DD + quad * 32;
#pragma unroll
    for (int mi = 0; mi < 2; ++mi)
#pragma unroll
      for (int ks = 0; ks < 2; ++ks)
        a_frag[mi][ks] = fragG(ab + mi * 16 * DD + ks * 128);
  }

  // ---- stage B tile for ct=0 ----
#pragma unroll
  for (int q = 0; q < 8; ++q) {
    const int rb = q * 16 + wave * 4;           // wave-uniform base row
    const int r  = rb + quad;
    async_cp16(p8 + (size_t)(colbase + r) * DD + ((l16 ^ (r & 15)) << 4),
               &Bs[rb * DD]);
  }

  float se_run[2][4], mx_run[2][4];
#pragma unroll
  for (int a = 0; a < 2; ++a)
#pragma unroll
    for (int b = 0; b < 4; ++b) { se_run[a][b] = 0.f; mx_run[a][b] = -INFINITY; }

  for (int ct = 0; ct < NCT; ++ct) {
    __syncthreads();  // Bs[ct] staged & visible
    const int col0 = colbase + ct * BNC;
    const bool hasdiag = (blockIdx.y == blockIdx.x * NCT + ct);

    // ---- chunk 0: cols [col0, col0+64) ----
    floatx4 acc[2][4];
#pragma unroll
    for (int a = 0; a < 2; ++a)
#pragma unroll
      for (int b = 0; b < 4; ++b) acc[a][b] = (floatx4){0.f, 0.f, 0.f, 0.f};
#pragma unroll
    for (int ni = 0; ni < 4; ++ni) {
      const int8v bf0 = fragLDS(Bs, ni * 16 + l16, 0, quad, l16);
      const int8v bf1 = fragLDS(Bs, ni * 16 + l16, 1, quad, l16);
      acc[0][ni] = mfma_sc(a_frag[0][0], bf0, acc[0][ni]);
      acc[0][ni] = mfma_sc(a_frag[0][1], bf1, acc[0][ni]);
      acc[1][ni] = mfma_sc(a_frag[1][0], bf0, acc[1][ni]);
      acc[1][ni] = mfma_sc(a_frag[1][1], bf1, acc[1][ni]);
    }
    // chunk-0 epilogue (compiler interleaves this VALU/trans work with
    // chunk-1's independent ds_reads + MFMAs below)
    if (!hasdiag) {
#pragma unroll
      for (int mi = 0; mi < 2; ++mi)
#pragma unroll
        for (int reg = 0; reg < 4; ++reg)
#pragma unroll
          for (int ni = 0; ni < 4; ++ni) {
            const float s = acc[mi][ni][reg];
            se_run[mi][reg] += __expf(s * TEMP_INV);
            mx_run[mi][reg] = fmaxf(mx_run[mi][reg], s);
          }
    } else {
#pragma unroll
      for (int mi = 0; mi < 2; ++mi)
#pragma unroll
        for (int reg = 0; reg < 4; ++reg) {
          const int i = row0 + wave * 32 + mi * 16 + quad * 4 + reg;
#pragma unroll
          for (int ni = 0; ni < 4; ++ni) {
            const float s = acc[mi][ni][reg];
            const int j = col0 + ni * 16 + l16;
            se_run[mi][reg] += __expf(s * TEMP_INV);
            mx_run[mi][reg] = fmaxf(mx_run[mi][reg], (i == j) ? -INFINITY : s);
          }
        }
    }

    // ---- chunk 1: cols [col0+64, col0+128) ----
    floatx4 acc2[2][4];
#pragma unroll
    for (int a = 0; a < 2; ++a)
#pragma unroll
      for (int b = 0; b < 4; ++b) acc2[a][b] = (floatx4){0.f, 0.f, 0.f, 0.f};
#pragma unroll
    for (int ni = 0; ni < 4; ++ni) {
      const int8v bf0 = fragLDS(Bs, (ni + 4) * 16 + l16, 0, quad, l16);
      const int8v bf1 = fragLDS(Bs, (ni + 4) * 16 + l16, 1, quad, l16);
      acc2[0][ni] = mfma_sc(a_frag[0][0], bf0, acc2[0][ni]);
      acc2[0][ni] = mfma_sc(a_frag[0][1], bf1, acc2[0][ni]);
      acc2[1][ni] = mfma_sc(a_frag[1][0], bf0, acc2[1][ni]);
      acc2[1][ni] = mfma_sc(a_frag[1][1], bf1, acc2[1][ni]);
    }

    __syncthreads();  // all waves done reading Bs
    if (ct + 1 < NCT) {  // issue next tile's staging; covered by epilogue below
      const int colb = colbase + (ct + 1) * BNC;
#pragma unroll
      for (int q = 0; q < 8; ++q) {
        const int rb = q * 16 + wave * 4;
        const int r  = rb + quad;
        async_cp16(p8 + (size_t)(colb + r) * DD + ((l16 ^ (r & 15)) << 4),
                   &Bs[rb * DD]);
      }
    }

    // chunk-1 epilogue (covers the staging latency)
    if (!hasdiag) {
#pragma unroll
      for (int mi = 0; mi < 2; ++mi)
#pragma unroll
        for (int reg = 0; reg < 4; ++reg)
#pragma unroll
          for (int ni = 0; ni < 4; ++ni) {
            const float s = acc2[mi][ni][reg];
            se_run[mi][reg] += __expf(s * TEMP_INV);
            mx_run[mi][reg] = fmaxf(mx_run[mi][reg], s);
          }
    } else {
#pragma unroll
      for (int mi = 0; mi < 2; ++mi)
#pragma unroll
        for (int reg = 0; reg < 4; ++reg) {
          const int i = row0 + wave * 32 + mi * 16 + quad * 4 + reg;
#pragma unroll
          for (int ni = 0; ni < 4; ++ni) {
            const float s = acc2[mi][ni][reg];
            const int j = col0 + (ni + 4) * 16 + l16;
            se_run[mi][reg] += __expf(s * TEMP_INV);
            mx_run[mi][reg] = fmaxf(mx_run[mi][reg], (i == j) ? -INFINITY : s);
          }
        }
    }
  }

  // rows complete within the wave: 16-lane reduce, direct global store
#pragma unroll
  for (int mi = 0; mi < 2; ++mi) {
#pragma unroll
    for (int reg = 0; reg < 4; ++reg) {
      float se = se_run[mi][reg], mx = mx_run[mi][reg];
#pragma unroll
      for (int m = 1; m < 16; m <<= 1) {
        se += __shfl_xor(se, m, 64);
        mx = fmaxf(mx, __shfl_xor(mx, m, 64));
      }
      if (l16 == 0) {
        const int r = wave * 32 + mi * 16 + quad * 4 + reg;
        rsum[(size_t)blockIdx.x * Btot + row0 + r] = se;
        rmax[(size_t)blockIdx.x * Btot + row0 + r] = mx;
      }
    }
  }
}

// ---- kernel 3: per-row loss from partials, block-reduce, atomic mean ----
__global__ __launch_bounds__(256) void row_loss_kernel(
    const float* __restrict__ rsum, const float* __restrict__ rmax,
    const float* __restrict__ diag, float* __restrict__ out, int Btot, int NG) {
  const int i = blockIdx.x * 256 + threadIdx.x;
  float s = 0.f, m = -INFINITY;
  for (int c = 0; c < NG; ++c) {
    s += rsum[(size_t)c * Btot + i];
    m = fmaxf(m, rmax[(size_t)c * Btot + i]);
  }
  float rl = __logf(s + __expf(m * TEMP_INV)) - diag[i] * TEMP_INV;
#pragma unroll
  for (int mm = 32; mm >= 1; mm >>= 1) rl += __shfl_xor(rl, mm, 64);
  __shared__ float red[4];
  if ((threadIdx.x & 63) == 0) red[threadIdx.x >> 6] = rl;
  __syncthreads();
  if (threadIdx.x == 0)
    atomicAdd(out, (red[0] + red[1] + red[2] + red[3]) / (float)Btot);
}

extern "C" void kernel_launch(void* const* d_in, const int* in_sizes, int n_in,
                              void* d_out, int out_size, void* d_ws, size_t ws_size,
                              hipStream_t stream) {
  const float* anchor   = (const float*)d_in[0];
  const float* positive = (const float*)d_in[1];
  const int B  = in_sizes[0] / DD;     // 8192
  const int NG = B / (BNC * NCT);      // 16 column groups
  const size_t BD = (size_t)B * DD;

  // ws: a8(2MB) | p8(2MB) | rsum(NG*B) | rmax(NG*B) | diag(B)
  unsigned char* a8 = (unsigned char*)d_ws;
  unsigned char* p8 = a8 + BD;
  float* rsum  = (float*)(p8 + BD);
  float* rmax  = rsum + (size_t)NG * B;
  float* diag  = rmax + (size_t)NG * B;

  nrm_kernel<<<B / 4, 256, 0, stream>>>(anchor, positive, a8, p8, diag,
                                        (float*)d_out);
  dim3 g2(NG, B / BMR);
  gemm_stats<<<g2, 256, 0, stream>>>(a8, p8, rsum, rmax, B);
  row_loss_kernel<<<B / 256, 256, 0, stream>>>(rsum, rmax, diag, (float*)d_out, B, NG);
}

// Round 4
// 110.025 us; speedup vs baseline: 1.5320x; 1.1702x over previous
//
#include <hip/hip_runtime.h>
#include <hip/hip_bf16.h>

using floatx4 = __attribute__((ext_vector_type(4))) float;
using int4v   = __attribute__((ext_vector_type(4))) int;
using int8v   = __attribute__((ext_vector_type(8))) int;

#define TEMP_INV 14.285714285714286f  // 1/0.07
#define DD 256   // feature dim; one fp8 row = 256 B
#define BM 128
#define NCT 8    // column tiles per block -> grid 8x64 = 512 = 2 blocks/CU exact
#define SC1 127  // e8m0 exponent 127 -> scale 1.0

// ---- kernel 1: L2 normalize rows -> fp8 e4m3, exact fp8 diag dot, and ----
// ---- zero the output scalar. p8 is written FRAGMENT-MAJOR: within each  ----
// ---- 16-row group (4 KB), byte b of row r lands at                      ----
// ----   (r&~15)*256 + (b>>7)*2048 + ((b>>4)&1)*1024 + ((b>>5)&3)*256     ----
// ----   + (r&15)*16 + (b&15)                                             ----
// ---- so a wave's MFMA B-fragment half is ONE contiguous 1 KB load.      ----
__global__ __launch_bounds__(256) void nrm_kernel(
    const float* __restrict__ anchor, const float* __restrict__ positive,
    unsigned char* __restrict__ a8, unsigned char* __restrict__ p8,
    float* __restrict__ diag, float* __restrict__ out) {
  if (blockIdx.x == 0 && threadIdx.x == 0) out[0] = 0.f;  // stream-order visible
  const int wave = threadIdx.x >> 6;
  const int lane = threadIdx.x & 63;
  const int row  = blockIdx.x * 4 + wave;
  const float4 va = ((const float4*)(anchor   + (size_t)row * DD))[lane];
  const float4 vp = ((const float4*)(positive + (size_t)row * DD))[lane];
  float sa = va.x * va.x + va.y * va.y + va.z * va.z + va.w * va.w;
  float sp = vp.x * vp.x + vp.y * vp.y + vp.z * vp.z + vp.w * vp.w;
#pragma unroll
  for (int m = 32; m >= 1; m >>= 1) {
    sa += __shfl_xor(sa, m, 64);
    sp += __shfl_xor(sp, m, 64);
  }
  const float ka = 1.0f / fmaxf(sqrtf(sa), 1e-12f);
  const float kp = 1.0f / fmaxf(sqrtf(sp), 1e-12f);
  int pa = __builtin_amdgcn_cvt_pk_fp8_f32(va.x * ka, va.y * ka, 0, false);
  pa     = __builtin_amdgcn_cvt_pk_fp8_f32(va.z * ka, va.w * ka, pa, true);
  int pp = __builtin_amdgcn_cvt_pk_fp8_f32(vp.x * kp, vp.y * kp, 0, false);
  pp     = __builtin_amdgcn_cvt_pk_fp8_f32(vp.z * kp, vp.w * kp, pp, true);
  // A stays row-major (read once per gemm block)
  ((int*)(a8 + (size_t)row * DD))[lane] = pa;
  // P fragment-major scatter: this lane's 4 bytes are b0=4*lane .. b0+3,
  // all inside one 16 B chunk (b0&15 in {0,4,8,12}).
  {
    const unsigned int off =
        (unsigned)(row & ~15) * DD            // group base (row>>4)*4096
        + ((lane >> 5) << 11)                 // ks   * 2048
        + (((lane >> 2) & 1) << 10)           // half * 1024
        + (((lane >> 3) & 3) << 8)            // quad * 256
        + ((row & 15) << 4)                   // rr   * 16
        + ((lane & 3) << 2);                  // byte-in-chunk
    *(int*)(p8 + off) = pp;
  }
  // exact quantized dot for the diagonal (byte selector must be literal)
  float d = __builtin_amdgcn_cvt_f32_fp8(pa, 0) * __builtin_amdgcn_cvt_f32_fp8(pp, 0)
          + __builtin_amdgcn_cvt_f32_fp8(pa, 1) * __builtin_amdgcn_cvt_f32_fp8(pp, 1)
          + __builtin_amdgcn_cvt_f32_fp8(pa, 2) * __builtin_amdgcn_cvt_f32_fp8(pp, 2)
          + __builtin_amdgcn_cvt_f32_fp8(pa, 3) * __builtin_amdgcn_cvt_f32_fp8(pp, 3);
#pragma unroll
  for (int m = 32; m >= 1; m >>= 1) d += __shfl_xor(d, m, 64);
  if (lane == 0) diag[row] = d;
}

// A fragment straight from global (row-major, per-lane gather, once/kernel).
__device__ __forceinline__ int8v fragG(const unsigned char* g) {
  const int4v lo = *(const int4v*)(g);
  const int4v hi = *(const int4v*)(g + 16);
  return __builtin_shufflevector(lo, hi, 0, 1, 2, 3, 4, 5, 6, 7);
}

__device__ __forceinline__ floatx4 mfma_sc(int8v a, int8v b, floatx4 c) {
  return __builtin_amdgcn_mfma_scale_f32_16x16x128_f8f6f4(a, b, c, 0, 0, 0,
                                                          SC1, 0, SC1);
}

// ------ kernel 2: 512 threads / 8 waves, 32x64 frags per wave ------
// R0 grid + wave decomposition (proven L2-optimal: wgid%8 = col group ->
// each XCD serves one 256 KB slice of p8). Change vs R0: NO LDS staging,
// NO main-loop barriers. B fragments are loaded straight from the
// fragment-major p8 (each half = contiguous 1 KB dwordx4, L1/L2-resident);
// A fragments live in registers (ct-invariant). 16 independent waves/CU
// self-overlap VMEM, MFMA and the exp epilogue with no convoy.
// MFMA chains + epilogue order bitwise-identical to R0.
__global__ __launch_bounds__(512, 4) void gemm_stats(
    const unsigned char* __restrict__ a8, const unsigned char* __restrict__ p8,
    float* __restrict__ rsum, float* __restrict__ rmax, int Btot) {
  __shared__ float red_sum[2][BM];
  __shared__ float red_max[2][BM];

  const int t = threadIdx.x;
  const int wave = t >> 6, lane = t & 63;
  const int wm = wave & 3, wn = wave >> 2;      // 4 row-groups x 2 col-groups
  const int quad = lane >> 4, l16 = lane & 15;
  const int row0    = blockIdx.y * BM;
  const int colbase = blockIdx.x * (NCT * BM);
  const bool hasdiag = ((int)(blockIdx.y >> 3) == (int)blockIdx.x);

  // ---- A fragments: 32 VGPRs, ct-invariant ----
  // rows row0 + wm*32 + mi*16 + l16, K bytes [ks*128 + quad*32, +32)
  int8v a_frag[2][2];
  {
    const unsigned char* ab =
        a8 + (size_t)(row0 + wm * 32 + l16) * DD + quad * 32;
#pragma unroll
    for (int mi = 0; mi < 2; ++mi)
#pragma unroll
      for (int ks = 0; ks < 2; ++ks)
        a_frag[mi][ks] = fragG(ab + mi * 16 * DD + ks * 128);
  }

  float se_run[2][4], mx_run[2][4];
#pragma unroll
  for (int a = 0; a < 2; ++a)
#pragma unroll
    for (int b = 0; b < 4; ++b) { se_run[a][b] = 0.f; mx_run[a][b] = -INFINITY; }

  for (int ct = 0; ct < NCT; ++ct) {
    const int col0 = colbase + ct * BM;
    // fragment-major base for this wave's 64 B-rows: rows col0+wn*64 ...
    // (16-aligned base X -> group base byte offset is X*256)
    const unsigned char* bb = p8 + (size_t)(col0 + wn * 64) * DD + lane * 16;

    floatx4 acc[2][4];
#pragma unroll
    for (int a = 0; a < 2; ++a)
#pragma unroll
      for (int b = 0; b < 4; ++b) acc[a][b] = (floatx4){0.f, 0.f, 0.f, 0.f};

#pragma unroll
    for (int ks = 0; ks < 2; ++ks) {
#pragma unroll
      for (int ni = 0; ni < 4; ++ni) {
        const unsigned char* c = bb + ni * 4096 + ks * 2048;
        const int4v lo = *(const int4v*)(c);          // contiguous 1 KB/wave
        const int4v hi = *(const int4v*)(c + 1024);   // contiguous 1 KB/wave
        const int8v bf = __builtin_shufflevector(lo, hi, 0, 1, 2, 3, 4, 5, 6, 7);
        acc[0][ni] = mfma_sc(a_frag[0][ks], bf, acc[0][ni]);
        acc[1][ni] = mfma_sc(a_frag[1][ks], bf, acc[1][ni]);
      }
    }

    // ---- fused stats epilogue (C/D: col=lane&15, row=quad*4+reg) ----
    if (!hasdiag) {
#pragma unroll
      for (int mi = 0; mi < 2; ++mi)
#pragma unroll
        for (int reg = 0; reg < 4; ++reg)
#pragma unroll
          for (int ni = 0; ni < 4; ++ni) {
            const float s = acc[mi][ni][reg];
            se_run[mi][reg] += __expf(s * TEMP_INV);
            mx_run[mi][reg] = fmaxf(mx_run[mi][reg], s);
          }
    } else {
#pragma unroll
      for (int mi = 0; mi < 2; ++mi)
#pragma unroll
        for (int reg = 0; reg < 4; ++reg) {
          const int i = row0 + wm * 32 + mi * 16 + quad * 4 + reg;
#pragma unroll
          for (int ni = 0; ni < 4; ++ni) {
            const float s = acc[mi][ni][reg];
            const int j = col0 + wn * 64 + ni * 16 + l16;
            se_run[mi][reg] += __expf(s * TEMP_INV);
            mx_run[mi][reg] = fmaxf(mx_run[mi][reg], (i == j) ? -INFINITY : s);
          }
        }
    }
  }

  // once-per-block 16-lane cross reduction, then cross-wn combine via LDS
#pragma unroll
  for (int mi = 0; mi < 2; ++mi) {
#pragma unroll
    for (int reg = 0; reg < 4; ++reg) {
      float se = se_run[mi][reg], mx = mx_run[mi][reg];
#pragma unroll
      for (int m = 1; m < 16; m <<= 1) {
        se += __shfl_xor(se, m, 64);
        mx = fmaxf(mx, __shfl_xor(mx, m, 64));
      }
      if (l16 == 0) {
        const int rb = wm * 32 + mi * 16 + quad * 4 + reg;
        red_sum[wn][rb] = se;
        red_max[wn][rb] = mx;
      }
    }
  }
  __syncthreads();
  if (t < BM) {
    rsum[(size_t)blockIdx.x * Btot + row0 + t] = red_sum[0][t] + red_sum[1][t];
    rmax[(size_t)blockIdx.x * Btot + row0 + t] = fmaxf(red_max[0][t], red_max[1][t]);
  }
}

// ---- kernel 3: per-row loss from partials, block-reduce, atomic mean ----
__global__ __launch_bounds__(256) void row_loss_kernel(
    const float* __restrict__ rsum, const float* __restrict__ rmax,
    const float* __restrict__ diag, float* __restrict__ out, int Btot, int NG) {
  const int i = blockIdx.x * 256 + threadIdx.x;
  float s = 0.f, m = -INFINITY;
  for (int c = 0; c < NG; ++c) {
    s += rsum[(size_t)c * Btot + i];
    m = fmaxf(m, rmax[(size_t)c * Btot + i]);
  }
  float rl = __logf(s + __expf(m * TEMP_INV)) - diag[i] * TEMP_INV;
#pragma unroll
  for (int mm = 32; mm >= 1; mm >>= 1) rl += __shfl_xor(rl, mm, 64);
  __shared__ float red[4];
  if ((threadIdx.x & 63) == 0) red[threadIdx.x >> 6] = rl;
  __syncthreads();
  if (threadIdx.x == 0)
    atomicAdd(out, (red[0] + red[1] + red[2] + red[3]) / (float)Btot);
}

extern "C" void kernel_launch(void* const* d_in, const int* in_sizes, int n_in,
                              void* d_out, int out_size, void* d_ws, size_t ws_size,
                              hipStream_t stream) {
  const float* anchor   = (const float*)d_in[0];
  const float* positive = (const float*)d_in[1];
  const int B  = in_sizes[0] / DD;     // 8192
  const int NG = B / (BM * NCT);       // 8 column groups
  const size_t BD = (size_t)B * DD;

  // ws: a8(2MB) | p8(2MB, fragment-major) | rsum(NG*B) | rmax(NG*B) | diag(B)
  unsigned char* a8 = (unsigned char*)d_ws;
  unsigned char* p8 = a8 + BD;
  float* rsum  = (float*)(p8 + BD);
  float* rmax  = rsum + (size_t)NG * B;
  float* diag  = rmax + (size_t)NG * B;

  nrm_kernel<<<B / 4, 256, 0, stream>>>(anchor, positive, a8, p8, diag,
                                        (float*)d_out);
  dim3 g2(NG, B / BM);
  gemm_stats<<<g2, 512, 0, stream>>>(a8, p8, rsum, rmax, B);
  row_loss_kernel<<<B / 256, 256, 0, stream>>>(rsum, rmax, diag, (float*)d_out, B, NG);
}